// Round 10
// baseline (124.471 us; speedup 1.0000x reference)
//
#include <hip/hip_runtime.h>
#include <hip/hip_bf16.h>

// Problem constants
#define B_  2
#define S_  2048
#define E_  512
#define H_  8
#define D_  64
#define BS_ (B_ * S_)   // 4096 rows
#define N1_ 1536        // fused tri-projection output cols
#define K_  512

typedef __bf16 bf16x8 __attribute__((ext_vector_type(8)));
typedef float  f32x4  __attribute__((ext_vector_type(4)));
typedef unsigned short us8 __attribute__((ext_vector_type(8)));

// float -> bf16 (RNE) bit trick
__device__ __forceinline__ ushort f2bf(float f) {
    unsigned u = __float_as_uint(f);
    unsigned r = (u + 0x7FFFu + ((u >> 16) & 1u)) >> 16;
    return (ushort)r;
}
__device__ __forceinline__ float bf2f(ushort b) {
    return __uint_as_float(((unsigned)b) << 16);
}

// async global->LDS, 16 B per lane; LDS dest = wave-uniform base + lane*16
__device__ __forceinline__ void gld_lds16(const ushort* g, ushort* l) {
    __builtin_amdgcn_global_load_lds(
        (const __attribute__((address_space(1))) unsigned int*)g,
        (__attribute__((address_space(3))) unsigned int*)l, 16, 0, 0);
}

// ================= GEMM1: PCS = x @ [Wp|Wc|Ws] + [bp|bc|bs] ==================
// Inline fp32 staging (no prep pass): A from x (k-contiguous, convert only),
// B from Wp/Wc/Ws (4x4 patch in-register transpose + convert). 128x96 tile,
// 256 thr = 4 waves (2x2), per-wave 4x3 frags of 16x16x32. LDS rows padded
// +8 shorts (144 B stride: 16B-aligned for ds_read_b128, spreads write banks).
__global__ __launch_bounds__(256) void gemm1_kernel(
    const float* __restrict__ x,
    const float* __restrict__ Wp, const float* __restrict__ Wc,
    const float* __restrict__ Ws,
    const float* __restrict__ bp, const float* __restrict__ bc,
    const float* __restrict__ bs,
    ushort* __restrict__ PCS) {
    constexpr int TM = 128, TN = 96, TK = 64, LDP = 72;
    __shared__ ushort As[TM][LDP];   // 18 KB
    __shared__ ushort Bs[TN][LDP];   // 13.5 KB

    const int tid  = threadIdx.x;
    const int lane = tid & 63;
    const int wave = tid >> 6;
    const int wm = wave >> 1, wn = wave & 1;
    const int row0 = blockIdx.y * TM;
    const int col0 = blockIdx.x * TN;

    f32x4 acc[4][3] = {};

    const int ar  = tid >> 4;        // A: row slice 0..15 (row = j*16 + ar)
    const int ac4 = tid & 15;        // A: float4 index within 64-k tile
    const int lrow = lane & 15;
    const int lk   = (lane >> 4) * 8;

    for (int kt = 0; kt < K_; kt += TK) {
        // ---- A: 8 float4/thread from x[row][kt + ac4*4], convert, b64 write
        #pragma unroll
        for (int j = 0; j < 8; j++) {
            int row = j * 16 + ar;
            float4 v = *(const float4*)(x + (size_t)(row0 + row) * K_ + kt + ac4 * 4);
            ushort4 h;
            h.x = f2bf(v.x); h.y = f2bf(v.y); h.z = f2bf(v.z); h.w = f2bf(v.w);
            *(ushort4*)(&As[row][ac4 * 4]) = h;
        }
        // ---- B: 4k x 4n patches; 384 patches over 1.5 rounds of 256 threads
        #pragma unroll
        for (int rd = 0; rd < 2; rd++) {
            int pid = rd * 256 + tid;
            if (pid < 384) {
                int pk = pid / 24, pn = pid % 24;    // pk 0..15, pn 0..23
                int gc = col0 + pn * 4;
                const float* Wseg = (gc < 512) ? (Wp + gc)
                                  : (gc < 1024) ? (Wc + gc - 512)
                                  : (Ws + gc - 1024);
                float4 r0 = *(const float4*)(Wseg + (size_t)(kt + pk * 4 + 0) * 512);
                float4 r1 = *(const float4*)(Wseg + (size_t)(kt + pk * 4 + 1) * 512);
                float4 r2 = *(const float4*)(Wseg + (size_t)(kt + pk * 4 + 2) * 512);
                float4 r3 = *(const float4*)(Wseg + (size_t)(kt + pk * 4 + 3) * 512);
                ushort4 h;
                h.x = f2bf(r0.x); h.y = f2bf(r1.x); h.z = f2bf(r2.x); h.w = f2bf(r3.x);
                *(ushort4*)(&Bs[pn * 4 + 0][pk * 4]) = h;
                h.x = f2bf(r0.y); h.y = f2bf(r1.y); h.z = f2bf(r2.y); h.w = f2bf(r3.y);
                *(ushort4*)(&Bs[pn * 4 + 1][pk * 4]) = h;
                h.x = f2bf(r0.z); h.y = f2bf(r1.z); h.z = f2bf(r2.z); h.w = f2bf(r3.z);
                *(ushort4*)(&Bs[pn * 4 + 2][pk * 4]) = h;
                h.x = f2bf(r0.w); h.y = f2bf(r1.w); h.z = f2bf(r2.w); h.w = f2bf(r3.w);
                *(ushort4*)(&Bs[pn * 4 + 3][pk * 4]) = h;
            }
        }
        __syncthreads();

        #pragma unroll
        for (int kk = 0; kk < TK; kk += 32) {
            bf16x8 af[4], bfr[3];
            #pragma unroll
            for (int i = 0; i < 4; i++)
                af[i] = *(const bf16x8*)(&As[wm * 64 + i * 16 + lrow][kk + lk]);
            #pragma unroll
            for (int j = 0; j < 3; j++)
                bfr[j] = *(const bf16x8*)(&Bs[wn * 48 + j * 16 + lrow][kk + lk]);
            #pragma unroll
            for (int i = 0; i < 4; i++)
                #pragma unroll
                for (int j = 0; j < 3; j++)
                    acc[i][j] = __builtin_amdgcn_mfma_f32_16x16x32_bf16(
                        af[i], bfr[j], acc[i][j], 0, 0, 0);
        }
        __syncthreads();
    }

    // C/D layout: col = lane&15, row = (lane>>4)*4 + reg  [m89/m91 verified]
    const int ccol = lane & 15;
    const int crow = (lane >> 4) * 4;
    #pragma unroll
    for (int j = 0; j < 3; j++) {
        int gcol = col0 + wn * 48 + j * 16 + ccol;
        float bias = (gcol < 512) ? bp[gcol]
                   : (gcol < 1024) ? bc[gcol - 512] : bs[gcol - 1024];
        #pragma unroll
        for (int i = 0; i < 4; i++) {
            int grow = row0 + wm * 64 + i * 16 + crow;
            #pragma unroll
            for (int rg = 0; rg < 4; rg++)
                PCS[(size_t)(grow + rg) * N1_ + gcol] = f2bf(acc[i][j][rg] + bias);
        }
    }
}

// ================= GEMM2: out = attn @ Wo + bo ==================
// A (attn, bf16) staged async via global_load_lds (unpadded LDS, layout-exact);
// B staged inline from fp32 Wo with 4x4 patch transpose. 64x64 tile.
__global__ __launch_bounds__(256) void gemm2_kernel(
    const ushort* __restrict__ A,    // 4096 x 512 bf16
    const float* __restrict__ Wo, const float* __restrict__ bo,
    float* __restrict__ out) {
    constexpr int TM = 64, TN = 64, TK = 64, LDP = 72;
    __shared__ ushort As[TM][TK];    // 8 KB, unpadded (async staging)
    __shared__ ushort Bs[TN][LDP];   // 9 KB

    const int tid  = threadIdx.x;
    const int lane = tid & 63;
    const int wave = tid >> 6;
    const int wm = wave >> 1, wn = wave & 1;
    const int row0 = blockIdx.y * TM;
    const int col0 = blockIdx.x * TN;

    f32x4 acc[2][2] = {};

    const int srow = lane >> 3;          // async A: 8-row issue slice
    const int scol = (lane & 7) * 8;
    const int pk = tid >> 4, pn = tid & 15;  // B patch coords
    const int lrow = lane & 15;
    const int lk   = (lane >> 4) * 8;

    for (int kt = 0; kt < K_; kt += TK) {
        const ushort* ga = A + (size_t)(row0 + wave * 16 + srow) * K_ + kt + scol;
        gld_lds16(ga,            &As[wave * 16 + 0][0]);
        gld_lds16(ga + 8 * K_,   &As[wave * 16 + 8][0]);

        {
            const float* Wseg = Wo + col0 + pn * 4;
            float4 r0 = *(const float4*)(Wseg + (size_t)(kt + pk * 4 + 0) * 512);
            float4 r1 = *(const float4*)(Wseg + (size_t)(kt + pk * 4 + 1) * 512);
            float4 r2 = *(const float4*)(Wseg + (size_t)(kt + pk * 4 + 2) * 512);
            float4 r3 = *(const float4*)(Wseg + (size_t)(kt + pk * 4 + 3) * 512);
            ushort4 h;
            h.x = f2bf(r0.x); h.y = f2bf(r1.x); h.z = f2bf(r2.x); h.w = f2bf(r3.x);
            *(ushort4*)(&Bs[pn * 4 + 0][pk * 4]) = h;
            h.x = f2bf(r0.y); h.y = f2bf(r1.y); h.z = f2bf(r2.y); h.w = f2bf(r3.y);
            *(ushort4*)(&Bs[pn * 4 + 1][pk * 4]) = h;
            h.x = f2bf(r0.z); h.y = f2bf(r1.z); h.z = f2bf(r2.z); h.w = f2bf(r3.z);
            *(ushort4*)(&Bs[pn * 4 + 2][pk * 4]) = h;
            h.x = f2bf(r0.w); h.y = f2bf(r1.w); h.z = f2bf(r2.w); h.w = f2bf(r3.w);
            *(ushort4*)(&Bs[pn * 4 + 3][pk * 4]) = h;
        }
        __syncthreads();

        #pragma unroll
        for (int kk = 0; kk < TK; kk += 32) {
            bf16x8 af[2], bfr[2];
            #pragma unroll
            for (int i = 0; i < 2; i++)
                af[i] = *(const bf16x8*)(&As[wm * 32 + i * 16 + lrow][kk + lk]);
            #pragma unroll
            for (int j = 0; j < 2; j++)
                bfr[j] = *(const bf16x8*)(&Bs[wn * 32 + j * 16 + lrow][kk + lk]);
            #pragma unroll
            for (int i = 0; i < 2; i++)
                #pragma unroll
                for (int j = 0; j < 2; j++)
                    acc[i][j] = __builtin_amdgcn_mfma_f32_16x16x32_bf16(
                        af[i], bfr[j], acc[i][j], 0, 0, 0);
        }
        __syncthreads();
    }

    const int ccol = lane & 15;
    const int crow = (lane >> 4) * 4;
    #pragma unroll
    for (int j = 0; j < 2; j++) {
        int gcol = col0 + wn * 32 + j * 16 + ccol;
        float bias = bo[gcol];
        #pragma unroll
        for (int i = 0; i < 2; i++) {
            int grow = row0 + wm * 32 + i * 16 + crow;
            #pragma unroll
            for (int rg = 0; rg < 4; rg++)
                out[(size_t)(grow + rg) * E_ + gcol] = acc[i][j][rg] + bias;
        }
    }
}

// ---------------- tree attention: 16B/lane ballot-scan gather ----------------
// PCS (bf16) row layout per token w (1536): [p(512)|c(512)|s(512)], each h*64+d.
// One wave per row n. Lane L owns 8 consecutive elements at offset L*8 of each
// 512-segment: head h = L>>3. Per edge: two dwordx4 loads, 8-FMA dot partial,
// shfl_xor(1,2,4) head-group reduce, one exp, 8 FMAs. Neighbor set
// {parent[n]} ∪ {m:parent[m]==n} minus duplicates, fixed order -> deterministic.
// NOTE: alpha is PER-HEAD — the s@Wo pre-fold is invalid (round-7 post-mortem).
__global__ __launch_bounds__(256) void attn_gather_kernel(
    const ushort* __restrict__ PCS, const int* __restrict__ parent,
    ushort* __restrict__ attn) {
    int gtid = blockIdx.x * blockDim.x + threadIdx.x;
    int w    = gtid >> 6;        // token row 0..BS_-1
    int lane = gtid & 63;
    int bbase = ((w >> 11) << 11);
    int i  = w & (S_ - 1);
    int rp = bbase + parent[w];

    // p fragment: 8 consecutive bf16 at w*1536 + lane*8
    float pnf[8];
    {
        us8 p8 = *(const us8*)(PCS + (size_t)w * N1_ + lane * 8);
        #pragma unroll
        for (int j = 0; j < 8; j++) pnf[j] = bf2f(p8[j]);
    }

    float Z, av[8];
    // parent edge (always present in the mask)
    {
        const ushort* rm = PCS + (size_t)rp * N1_;
        us8 c8 = *(const us8*)(rm + 512  + lane * 8);
        us8 s8 = *(const us8*)(rm + 1024 + lane * 8);
        float t = 0.f;
        #pragma unroll
        for (int j = 0; j < 8; j++) t += pnf[j] * bf2f(c8[j]);
        t += __shfl_xor(t, 1); t += __shfl_xor(t, 2); t += __shfl_xor(t, 4);
        float e = __expf(t * 0.125f);          // 1/sqrt(D) = 1/8
        Z = e;
        #pragma unroll
        for (int j = 0; j < 8; j++) av[j] = e * bf2f(s8[j]);
    }

    // children: scan this batch's parent slice, 256 ints per step (int4/lane)
    for (int t0 = 0; t0 < S_; t0 += 256) {
        int4 pv = *(const int4*)(parent + bbase + t0 + lane * 4);
        int pc[4] = {pv.x, pv.y, pv.z, pv.w};
        #pragma unroll
        for (int jj = 0; jj < 4; jj++) {
            unsigned long long mask = __ballot(pc[jj] == i);
            while (mask) {
                int l = __ffsll(mask) - 1;
                mask &= mask - 1;
                int c = bbase + t0 + l * 4 + jj;
                if (c == rp) continue;         // mutual/self edge counted once
                const ushort* rc = PCS + (size_t)c * N1_;
                us8 c8 = *(const us8*)(rc + 512  + lane * 8);
                us8 s8 = *(const us8*)(rc + 1024 + lane * 8);
                float t = 0.f;
                #pragma unroll
                for (int j = 0; j < 8; j++) t += pnf[j] * bf2f(c8[j]);
                t += __shfl_xor(t, 1); t += __shfl_xor(t, 2); t += __shfl_xor(t, 4);
                float e = __expf(t * 0.125f);
                Z += e;
                #pragma unroll
                for (int j = 0; j < 8; j++) av[j] += e * bf2f(s8[j]);
            }
        }
    }

    float rz = 1.0f / Z;
    us8 o8;
    #pragma unroll
    for (int j = 0; j < 8; j++) o8[j] = f2bf(av[j] * rz);
    *(us8*)(attn + (size_t)w * E_ + lane * 8) = o8;
}

// ---------------- launch ----------------
extern "C" void kernel_launch(void* const* d_in, const int* in_sizes, int n_in,
                              void* d_out, int out_size, void* d_ws, size_t ws_size,
                              hipStream_t stream) {
    const float* x      = (const float*)d_in[0];
    const int*   parent = (const int*)  d_in[1];
    const float* Wp     = (const float*)d_in[2];
    const float* bp     = (const float*)d_in[3];
    const float* Wc     = (const float*)d_in[4];
    const float* bc     = (const float*)d_in[5];
    const float* Ws     = (const float*)d_in[6];
    const float* bs     = (const float*)d_in[7];
    const float* Wo     = (const float*)d_in[8];
    const float* bo     = (const float*)d_in[9];
    float* out = (float*)d_out;

    char* ws = (char*)d_ws;
    // workspace layout; every byte read is written earlier in the same call
    ushort* PCS_bf  = (ushort*)(ws + 0);          // 12,582,912
    ushort* attn_bf = (ushort*)(ws + 12582912);   //  4,194,304  (end ~16.8 MB)

    // GEMM1 (inline fp32 staging, no prep): 16x32 = 512 blocks = 2.0/CU
    gemm1_kernel<<<dim3(N1_ / 96, BS_ / 128), 256, 0, stream>>>(
        x, Wp, Wc, Ws, bp, bc, bs, PCS_bf);

    // tree attention: deterministic gather, 16B/lane loads, no atomics
    attn_gather_kernel<<<BS_ * 64 / 256, 256, 0, stream>>>(
        PCS_bf, parent, attn_bf);

    // GEMM2 (async A, inline fp32 B): 8x64 = 512 blocks = 2.0/CU
    gemm2_kernel<<<dim3(E_ / 64, BS_ / 64), 256, 0, stream>>>(
        attn_bf, Wo, bo, out);
}